// Round 1
// baseline (571.238 us; speedup 1.0000x reference)
//
#include <hip/hip_runtime.h>
#include <math.h>

// SGC: out = log_softmax( S^3 * x * (W1*W2*W3) )
// S = scatter-add over edges (dst += src). Weight collapse is valid since
// S acts on rows (nodes) and W on cols (features).

// ---------- tiny weight-collapse GEMMs ----------
// W12 = W1(128x64) @ W2(64x64)
__global__ void k_w12(const float* __restrict__ W1, const float* __restrict__ W2,
                      float* __restrict__ W12) {
    int idx = blockIdx.x * blockDim.x + threadIdx.x;   // 8192 elems
    if (idx >= 128 * 64) return;
    int r = idx >> 6, c = idx & 63;
    float acc = 0.f;
#pragma unroll
    for (int k = 0; k < 64; ++k) acc += W1[r * 64 + k] * W2[k * 64 + c];
    W12[idx] = acc;
}

// Wc = W12(128x64) @ W3(64x40)
__global__ void k_wc(const float* __restrict__ W12, const float* __restrict__ W3,
                     float* __restrict__ Wc) {
    int idx = blockIdx.x * blockDim.x + threadIdx.x;   // 5120 elems
    if (idx >= 128 * 40) return;
    int r = idx / 40, c = idx - r * 40;
    float acc = 0.f;
#pragma unroll
    for (int k = 0; k < 64; ++k) acc += W12[r * 64 + k] * W3[k * 40 + c];
    Wc[idx] = acc;
}

// ---------- y0 = x(N x 128) @ Wc(128x40), row-major ----------
// 5 threads per node, each computes 8 consecutive j (two float4), Wc in LDS.
__global__ void k_gemm(const float4* __restrict__ x4, const float4* __restrict__ Wc4,
                       float4* __restrict__ y4, int n_nodes) {
    __shared__ float4 wc[128 * 10];
    for (int i = threadIdx.x; i < 1280; i += blockDim.x) wc[i] = Wc4[i];
    __syncthreads();
    int tid = blockIdx.x * blockDim.x + threadIdx.x;
    int node = tid / 5, j0 = tid - node * 5;
    if (node >= n_nodes) return;
    float4 a0 = {0.f, 0.f, 0.f, 0.f}, a1 = {0.f, 0.f, 0.f, 0.f};
    const float4* xr = x4 + (size_t)node * 32;
#pragma unroll
    for (int k4 = 0; k4 < 32; ++k4) {
        float4 v = xr[k4];
#pragma unroll
        for (int kk = 0; kk < 4; ++kk) {
            float c = (kk == 0) ? v.x : (kk == 1) ? v.y : (kk == 2) ? v.z : v.w;
            float4 w0 = wc[(k4 * 4 + kk) * 10 + j0 * 2];
            float4 w1 = wc[(k4 * 4 + kk) * 10 + j0 * 2 + 1];
            a0.x += c * w0.x; a0.y += c * w0.y; a0.z += c * w0.z; a0.w += c * w0.w;
            a1.x += c * w1.x; a1.y += c * w1.y; a1.z += c * w1.z; a1.w += c * w1.w;
        }
    }
    y4[(size_t)node * 10 + j0 * 2]     = a0;
    y4[(size_t)node * 10 + j0 * 2 + 1] = a1;
}

// ---------- CSR build ----------
__global__ void k_hist(const int* __restrict__ dst, int* __restrict__ counts, int E) {
    int e = blockIdx.x * blockDim.x + threadIdx.x;
    if (e < E) atomicAdd(&counts[dst[e]], 1);
}

// single-block exclusive scan of counts[n] -> offs[n+1]
__global__ void k_scan(const int* __restrict__ counts, int* __restrict__ offs, int n) {
    __shared__ int part[1024];
    int t = threadIdx.x;
    int chunk = (n + 1023) >> 10;
    int beg = t * chunk, end = min(beg + chunk, n);
    int s = 0;
    for (int i = beg; i < end; ++i) s += counts[i];
    part[t] = s;
    __syncthreads();
    for (int off = 1; off < 1024; off <<= 1) {
        int v = (t >= off) ? part[t - off] : 0;
        __syncthreads();
        part[t] += v;
        __syncthreads();
    }
    int run = (t == 0) ? 0 : part[t - 1];
    for (int i = beg; i < end; ++i) { offs[i] = run; run += counts[i]; }
    if (t == 0) offs[n] = part[1023];
}

__global__ void k_fill(const int* __restrict__ src, const int* __restrict__ dst,
                       int* __restrict__ cursor, int* __restrict__ ssort, int E) {
    int e = blockIdx.x * blockDim.x + threadIdx.x;
    if (e < E) {
        int pos = atomicAdd(&cursor[dst[e]], 1);
        ssort[pos] = src[e];
    }
}

// ---------- aggregation: yout[n] = sum_{e: dst=n} yin[src(e)], d=40 ----------
// one wave per node; lanes 0..39 carry features. FINAL fuses log_softmax.
template <int FINAL>
__global__ void k_agg(const float* __restrict__ yin, float* __restrict__ yout,
                      const int* __restrict__ offs, const int* __restrict__ srcs,
                      int n_nodes) {
    int wid = (blockIdx.x * blockDim.x + threadIdx.x) >> 6;
    int lane = threadIdx.x & 63;
    if (wid >= n_nodes) return;
    int beg = offs[wid], end = offs[wid + 1];
    float a0 = 0.f, a1 = 0.f, a2 = 0.f, a3 = 0.f;
    if (lane < 40) {
        int k = beg;
        for (; k + 4 <= end; k += 4) {
            int s0 = srcs[k], s1 = srcs[k + 1], s2 = srcs[k + 2], s3 = srcs[k + 3];
            a0 += yin[s0 * 40 + lane];
            a1 += yin[s1 * 40 + lane];
            a2 += yin[s2 * 40 + lane];
            a3 += yin[s3 * 40 + lane];
        }
        for (; k < end; ++k) a0 += yin[srcs[k] * 40 + lane];
    }
    float acc = (a0 + a1) + (a2 + a3);
    if (FINAL) {
        float mv = (lane < 40) ? acc : -INFINITY;
#pragma unroll
        for (int off = 32; off; off >>= 1) mv = fmaxf(mv, __shfl_xor(mv, off, 64));
        float ev = (lane < 40) ? __expf(acc - mv) : 0.f;
#pragma unroll
        for (int off = 32; off; off >>= 1) ev += __shfl_xor(ev, off, 64);
        float ls = __logf(ev);
        if (lane < 40) yout[wid * 40 + lane] = acc - mv - ls;
    } else {
        if (lane < 40) yout[wid * 40 + lane] = acc;
    }
}

extern "C" void kernel_launch(void* const* d_in, const int* in_sizes, int n_in,
                              void* d_out, int out_size, void* d_ws, size_t ws_size,
                              hipStream_t stream) {
    const float* x   = (const float*)d_in[0];
    const int* esrc  = (const int*)d_in[1];
    const int* edst  = (const int*)d_in[2];
    const float* W1  = (const float*)d_in[3];
    const float* W2  = (const float*)d_in[4];
    const float* W3  = (const float*)d_in[5];
    int N = in_sizes[0] / 128;
    int E = in_sizes[1];
    float* out = (float*)d_out;

    char* ws = (char*)d_ws;
    auto alloc = [&](size_t bytes) {
        char* p = ws;
        ws += (bytes + 255) & ~(size_t)255;
        return p;
    };
    float* bufA  = (float*)alloc((size_t)N * 40 * sizeof(float));
    float* bufB  = (float*)alloc((size_t)N * 40 * sizeof(float));
    float* W12   = (float*)alloc(128 * 64 * sizeof(float));
    float* Wc    = (float*)alloc(128 * 40 * sizeof(float));
    int* counts  = (int*)alloc((size_t)N * sizeof(int));
    int* offs    = (int*)alloc((size_t)(N + 1) * sizeof(int));
    int* cursor  = (int*)alloc((size_t)N * sizeof(int));
    int* ssort   = (int*)alloc((size_t)E * sizeof(int));

    hipMemsetAsync(counts, 0, (size_t)N * sizeof(int), stream);

    k_w12<<<(128 * 64 + 255) / 256, 256, 0, stream>>>(W1, W2, W12);
    k_wc<<<(128 * 40 + 255) / 256, 256, 0, stream>>>(W12, W3, Wc);
    k_gemm<<<(N * 5 + 255) / 256, 256, 0, stream>>>((const float4*)x, (const float4*)Wc,
                                                    (float4*)bufA, N);

    k_hist<<<(E + 255) / 256, 256, 0, stream>>>(edst, counts, E);
    k_scan<<<1, 1024, 0, stream>>>(counts, offs, N);
    hipMemcpyAsync(cursor, offs, (size_t)N * sizeof(int), hipMemcpyDeviceToDevice, stream);
    k_fill<<<(E + 255) / 256, 256, 0, stream>>>(esrc, edst, cursor, ssort, E);

    int agg_grid = (N * 64 + 255) / 256;
    k_agg<0><<<agg_grid, 256, 0, stream>>>(bufA, bufB, offs, ssort, N);
    k_agg<0><<<agg_grid, 256, 0, stream>>>(bufB, bufA, offs, ssort, N);
    k_agg<1><<<agg_grid, 256, 0, stream>>>(bufA, out, offs, ssort, N);
}

// Round 2
// 436.178 us; speedup vs baseline: 1.3096x; 1.3096x over previous
//
#include <hip/hip_runtime.h>
#include <math.h>

// SGC: out = log_softmax( S^3 * x * (W1*W2*W3) )
// S = scatter-add over edges (dst += src). Weight collapse is valid since
// S acts on rows (nodes) and W on cols (features).

// ---------- tiny weight-collapse GEMMs ----------
__global__ void k_w12(const float* __restrict__ W1, const float* __restrict__ W2,
                      float* __restrict__ W12) {
    int idx = blockIdx.x * blockDim.x + threadIdx.x;   // 8192 elems
    if (idx >= 128 * 64) return;
    int r = idx >> 6, c = idx & 63;
    float acc = 0.f;
#pragma unroll
    for (int k = 0; k < 64; ++k) acc += W1[r * 64 + k] * W2[k * 64 + c];
    W12[idx] = acc;
}

__global__ void k_wc(const float* __restrict__ W12, const float* __restrict__ W3,
                     float* __restrict__ Wc) {
    int idx = blockIdx.x * blockDim.x + threadIdx.x;   // 5120 elems
    if (idx >= 128 * 40) return;
    int r = idx / 40, c = idx - r * 40;
    float acc = 0.f;
#pragma unroll
    for (int k = 0; k < 64; ++k) acc += W12[r * 64 + k] * W3[k * 40 + c];
    Wc[idx] = acc;
}

// ---------- y0 = x(N x 128) @ Wc(128x40) ----------
__global__ void k_gemm(const float4* __restrict__ x4, const float4* __restrict__ Wc4,
                       float4* __restrict__ y4, int n_nodes) {
    __shared__ float4 wc[128 * 10];
    for (int i = threadIdx.x; i < 1280; i += blockDim.x) wc[i] = Wc4[i];
    __syncthreads();
    int tid = blockIdx.x * blockDim.x + threadIdx.x;
    int node = tid / 5, j0 = tid - node * 5;
    if (node >= n_nodes) return;
    float4 a0 = {0.f, 0.f, 0.f, 0.f}, a1 = {0.f, 0.f, 0.f, 0.f};
    const float4* xr = x4 + (size_t)node * 32;
#pragma unroll
    for (int k4 = 0; k4 < 32; ++k4) {
        float4 v = xr[k4];
#pragma unroll
        for (int kk = 0; kk < 4; ++kk) {
            float c = (kk == 0) ? v.x : (kk == 1) ? v.y : (kk == 2) ? v.z : v.w;
            float4 w0 = wc[(k4 * 4 + kk) * 10 + j0 * 2];
            float4 w1 = wc[(k4 * 4 + kk) * 10 + j0 * 2 + 1];
            a0.x += c * w0.x; a0.y += c * w0.y; a0.z += c * w0.z; a0.w += c * w0.w;
            a1.x += c * w1.x; a1.y += c * w1.y; a1.z += c * w1.z; a1.w += c * w1.w;
        }
    }
    y4[(size_t)node * 10 + j0 * 2]     = a0;
    y4[(size_t)node * 10 + j0 * 2 + 1] = a1;
}

// ---------- CSR build ----------
__global__ void k_hist(const int* __restrict__ dst, int* __restrict__ counts, int E) {
    int e = blockIdx.x * blockDim.x + threadIdx.x;
    if (e < E) atomicAdd(&counts[dst[e]], 1);
}

// 3-phase device-wide exclusive scan (2048 elems / block)
__global__ void k_bsum(const int* __restrict__ counts, int* __restrict__ bsum, int n) {
    int base = blockIdx.x * 2048;
    int t = threadIdx.x;
    int s = 0;
#pragma unroll
    for (int i = 0; i < 8; ++i) {
        int idx = base + t + i * 256;
        if (idx < n) s += counts[idx];
    }
    __shared__ int ws[4];
#pragma unroll
    for (int off = 32; off; off >>= 1) s += __shfl_down(s, off, 64);
    int wave = t >> 6, lane = t & 63;
    if (lane == 0) ws[wave] = s;
    __syncthreads();
    if (t == 0) bsum[blockIdx.x] = ws[0] + ws[1] + ws[2] + ws[3];
}

__global__ void k_bscan(const int* __restrict__ bsum, int* __restrict__ bpre,
                        int* __restrict__ offs, int nb, int n) {
    __shared__ int sh[1024];
    int t = threadIdx.x;
    int v0 = (t < nb) ? bsum[t] : 0;
    sh[t] = v0;
    __syncthreads();
    for (int off = 1; off < 1024; off <<= 1) {
        int v = (t >= off) ? sh[t - off] : 0;
        __syncthreads();
        sh[t] += v;
        __syncthreads();
    }
    if (t < nb) bpre[t] = sh[t] - v0;          // exclusive block prefix
    if (t == nb - 1) offs[n] = sh[t];          // total = E
}

__global__ void k_scan_fin(const int* __restrict__ counts, const int* __restrict__ bpre,
                           int* __restrict__ offs, int* __restrict__ cursor, int n) {
    __shared__ int sh[2048];
    __shared__ int wsum[4];
    int base = blockIdx.x * 2048;
    int t = threadIdx.x;
#pragma unroll
    for (int i = 0; i < 8; ++i) {
        int idx = base + t + i * 256;
        sh[t + i * 256] = (idx < n) ? counts[idx] : 0;
    }
    __syncthreads();
    int loc[8]; int s = 0;
#pragma unroll
    for (int i = 0; i < 8; ++i) { loc[i] = s; s += sh[t * 8 + i]; }
    int inc = s;
#pragma unroll
    for (int off = 1; off < 64; off <<= 1) {
        int v = __shfl_up(inc, off, 64);
        if ((t & 63) >= off) inc += v;
    }
    int wave = t >> 6, lane = t & 63;
    if (lane == 63) wsum[wave] = inc;
    __syncthreads();
    int woff = 0;
    for (int w = 0; w < wave; ++w) woff += wsum[w];
    int texc = woff + inc - s;
    int boff = bpre[blockIdx.x];
#pragma unroll
    for (int i = 0; i < 8; ++i) {
        int idx = base + t * 8 + i;
        if (idx < n) { int v = boff + texc + loc[i]; offs[idx] = v; cursor[idx] = v; }
    }
}

__global__ void k_fill(const int* __restrict__ src, const int* __restrict__ dst,
                       int* __restrict__ cursor, int* __restrict__ ssort, int E) {
    int e = blockIdx.x * blockDim.x + threadIdx.x;
    if (e < E) {
        int pos = atomicAdd(&cursor[dst[e]], 1);
        ssort[pos] = src[e];
    }
}

// ---------- aggregation ----------
template <int FINAL>
__global__ void k_agg(const float* __restrict__ yin, float* __restrict__ yout,
                      const int* __restrict__ offs, const int* __restrict__ srcs,
                      int n_nodes) {
    int wid = (blockIdx.x * blockDim.x + threadIdx.x) >> 6;
    int lane = threadIdx.x & 63;
    if (wid >= n_nodes) return;
    int beg = offs[wid], end = offs[wid + 1];
    float a0 = 0.f, a1 = 0.f, a2 = 0.f, a3 = 0.f;
    if (lane < 40) {
        int k = beg;
        for (; k + 4 <= end; k += 4) {
            int s0 = srcs[k], s1 = srcs[k + 1], s2 = srcs[k + 2], s3 = srcs[k + 3];
            a0 += yin[s0 * 40 + lane];
            a1 += yin[s1 * 40 + lane];
            a2 += yin[s2 * 40 + lane];
            a3 += yin[s3 * 40 + lane];
        }
        for (; k < end; ++k) a0 += yin[srcs[k] * 40 + lane];
    }
    float acc = (a0 + a1) + (a2 + a3);
    if (FINAL) {
        float mv = (lane < 40) ? acc : -INFINITY;
#pragma unroll
        for (int off = 32; off; off >>= 1) mv = fmaxf(mv, __shfl_xor(mv, off, 64));
        float ev = (lane < 40) ? __expf(acc - mv) : 0.f;
#pragma unroll
        for (int off = 32; off; off >>= 1) ev += __shfl_xor(ev, off, 64);
        float ls = __logf(ev);
        if (lane < 40) yout[wid * 40 + lane] = acc - mv - ls;
    } else {
        if (lane < 40) yout[wid * 40 + lane] = acc;
    }
}

extern "C" void kernel_launch(void* const* d_in, const int* in_sizes, int n_in,
                              void* d_out, int out_size, void* d_ws, size_t ws_size,
                              hipStream_t stream) {
    const float* x   = (const float*)d_in[0];
    const int* esrc  = (const int*)d_in[1];
    const int* edst  = (const int*)d_in[2];
    const float* W1  = (const float*)d_in[3];
    const float* W2  = (const float*)d_in[4];
    const float* W3  = (const float*)d_in[5];
    int N = in_sizes[0] / 128;
    int E = in_sizes[1];
    float* out = (float*)d_out;

    char* ws = (char*)d_ws;
    auto alloc = [&](size_t bytes) {
        char* p = ws;
        ws += (bytes + 255) & ~(size_t)255;
        return p;
    };
    float* bufA  = (float*)alloc((size_t)N * 40 * sizeof(float));
    float* bufB  = (float*)alloc((size_t)N * 40 * sizeof(float));
    float* W12   = (float*)alloc(128 * 64 * sizeof(float));
    float* Wc    = (float*)alloc(128 * 40 * sizeof(float));
    int* counts  = (int*)alloc((size_t)N * sizeof(int));
    int* offs    = (int*)alloc((size_t)(N + 1) * sizeof(int));
    int* cursor  = (int*)alloc((size_t)N * sizeof(int));
    int* bsum    = (int*)alloc(1024 * sizeof(int));
    int* bpre    = (int*)alloc(1024 * sizeof(int));
    int* ssort   = (int*)alloc((size_t)E * sizeof(int));

    hipMemsetAsync(counts, 0, (size_t)N * sizeof(int), stream);

    k_w12<<<(128 * 64 + 255) / 256, 256, 0, stream>>>(W1, W2, W12);
    k_wc<<<(128 * 40 + 255) / 256, 256, 0, stream>>>(W12, W3, Wc);
    k_gemm<<<(N * 5 + 255) / 256, 256, 0, stream>>>((const float4*)x, (const float4*)Wc,
                                                    (float4*)bufA, N);

    k_hist<<<(E + 255) / 256, 256, 0, stream>>>(edst, counts, E);
    int nb = (N + 2047) / 2048;
    k_bsum<<<nb, 256, 0, stream>>>(counts, bsum, N);
    k_bscan<<<1, 1024, 0, stream>>>(bsum, bpre, offs, nb, N);
    k_scan_fin<<<nb, 256, 0, stream>>>(counts, bpre, offs, cursor, N);
    k_fill<<<(E + 255) / 256, 256, 0, stream>>>(esrc, edst, cursor, ssort, E);

    int agg_grid = (N * 64 + 255) / 256;
    k_agg<0><<<agg_grid, 256, 0, stream>>>(bufA, bufB, offs, ssort, N);
    k_agg<0><<<agg_grid, 256, 0, stream>>>(bufB, bufA, offs, ssort, N);
    k_agg<1><<<agg_grid, 256, 0, stream>>>(bufA, out, offs, ssort, N);
}